// Round 1
// baseline (719.973 us; speedup 1.0000x reference)
//
#include <hip/hip_runtime.h>

// ---------------------------------------------------------------------------
// TypeSpecificProjection: out[v] = feat[v, :d_t] @ W_t + b_t,  t = type_ids[v]
// Strategy: bucket vertices by type (count/prefix/scatter), pre-swizzle W into
// MFMA B-fragment layout (bf16), then 4 type-templated bf16-MFMA GEMMs with
// row gather + LDS-transposed coalesced 1KB row stores.
// ---------------------------------------------------------------------------

typedef __attribute__((ext_vector_type(8))) __bf16 bf16x8;
typedef __attribute__((ext_vector_type(4))) __bf16 bf16x4;
typedef __attribute__((ext_vector_type(4))) float f32x4;

// ws layout (bytes):
//      0: counts[4]
//     16: cursors[4]
//     32: bases[4]
//     64: idx[500000]           (2,000,000 B, ends at 2,000,064)
// 2000128: wbuf bf16[81920]     (163,840 B)   total ~2.07 MiB
#define WS_WBUF_BYTES 2000128

// ---------------------------------------------------------------------------
__global__ void count_kernel(const int* __restrict__ types, int n,
                             int* __restrict__ counts) {
    __shared__ int h[4];
    if (threadIdx.x < 4) h[threadIdx.x] = 0;
    __syncthreads();
    for (int i = blockIdx.x * blockDim.x + threadIdx.x; i < n;
         i += gridDim.x * blockDim.x)
        atomicAdd(&h[types[i]], 1);
    __syncthreads();
    if (threadIdx.x < 4) atomicAdd(&counts[threadIdx.x], h[threadIdx.x]);
}

__global__ void bases_kernel(const int* __restrict__ counts,
                             int* __restrict__ bases, int* __restrict__ cursors) {
    if (threadIdx.x == 0) {
        int s = 0;
        for (int t = 0; t < 4; ++t) { bases[t] = s; cursors[t] = s; s += counts[t]; }
    }
}

// Block-aggregated scatter: 4 global atomics per block instead of 1 per thread.
__global__ void scatter_kernel(const int* __restrict__ types, int n,
                               int* __restrict__ cursors, int* __restrict__ idx) {
    __shared__ int h[4], hb[4], cur[4];
    const int tid = threadIdx.x;
    if (tid < 4) h[tid] = 0;
    __syncthreads();
    const int i0 = blockIdx.x * 1024;
    int myt[4];
    #pragma unroll
    for (int k = 0; k < 4; ++k) {
        int i = i0 + k * 256 + tid;
        myt[k] = (i < n) ? types[i] : -1;
        if (myt[k] >= 0) atomicAdd(&h[myt[k]], 1);
    }
    __syncthreads();
    if (tid < 4) { hb[tid] = atomicAdd(&cursors[tid], h[tid]); cur[tid] = 0; }
    __syncthreads();
    #pragma unroll
    for (int k = 0; k < 4; ++k) {
        if (myt[k] >= 0) {
            int p = atomicAdd(&cur[myt[k]], 1);
            idx[hb[myt[k]] + p] = i0 + k * 256 + tid;
        }
    }
}

// Pre-swizzle all 4 weight matrices into MFMA B-fragment order (bf16):
// element (t, c, nt, lane, j)  <-  W_t[c*32 + (lane>>4)*8 + j][nt*16 + (lane&15)]
__global__ void wswz_kernel(const float* __restrict__ W0, const float* __restrict__ W1,
                            const float* __restrict__ W2, const float* __restrict__ W3,
                            __bf16* __restrict__ wbuf) {
    int o = blockIdx.x * 256 + threadIdx.x;
    if (o >= 81920) return;
    const int woff[5] = {0, 16384, 49152, 73728, 81920};
    int t = 0;
    while (o >= woff[t + 1]) ++t;
    int rel = o - woff[t];
    int j    = rel & 7;
    int lane = (rel >> 3) & 63;
    int cb   = rel >> 9;          // (c*16 + nt)
    int c    = cb >> 4;
    int nt   = cb & 15;
    int k = c * 32 + (lane >> 4) * 8 + j;
    int n = nt * 16 + (lane & 15);
    const float* W = (t == 0) ? W0 : (t == 1) ? W1 : (t == 2) ? W2 : W3;
    wbuf[o] = (__bf16)W[k * 256 + n];
}

// ---------------------------------------------------------------------------
// GEMM per type: M = count_t (gathered rows), N = 256, K = d_t.
// Block: 256 threads (4 waves), M_TILE=64. Wave w owns cols [w*64, w*64+64).
// A staged fp32->bf16 in LDS (row stride K+8 to break bank conflicts);
// B read as coalesced 16B frags straight from the swizzled L2-resident wbuf.
// Epilogue: per-16-row LDS transpose -> one full 1KB contiguous row store
// per wave instruction (+bias).
// ---------------------------------------------------------------------------
template <int TT, int K, int WOFF>
__launch_bounds__(256, 3)
__global__ void gemm_kernel(const float* __restrict__ feat,
                            const int* __restrict__ ws_i,
                            const __bf16* __restrict__ wbuf,
                            const float* __restrict__ bias,
                            float* __restrict__ out) {
    const int cnt = ws_i[TT];                 // counts at int offset 0
    const int m0  = (int)blockIdx.x * 64;
    if (m0 >= cnt) return;
    const int base = ws_i[8 + TT];            // bases at byte 32
    const int* __restrict__ idxbuf = ws_i + 16;  // idx at byte 64
    const int mcount = min(64, cnt - m0);

    constexpr int LDA = K + 8;                // bf16 elements; +8 kills conflicts
    __shared__ __bf16 ldsA[64 * LDA];
    __shared__ float  ldsOut[16 * 260];       // 16 rows x 256 (+4 pad)
    __shared__ int    lidx[64];

    const int tid = threadIdx.x;
    if (tid < 64) lidx[tid] = (tid < mcount) ? idxbuf[base + m0 + tid] : 0;
    __syncthreads();

    // Stage A tile: gather rows, fp32 -> bf16.
    constexpr int K4 = K / 4;                 // float4 per row
    for (int f = tid; f < 64 * K4; f += 256) {
        int row = f / K4;                     // compile-time divisor
        int c4  = f - row * K4;
        if (row < mcount) {
            int g = lidx[row];
            f32x4 v = *reinterpret_cast<const f32x4*>(&feat[(size_t)g * 128 + c4 * 4]);
            bf16x4 h = {(__bf16)v.x, (__bf16)v.y, (__bf16)v.z, (__bf16)v.w};
            *reinterpret_cast<bf16x4*>(&ldsA[row * LDA + c4 * 4]) = h;
        }
    }
    __syncthreads();

    const int lane = tid & 63;
    const int wave = tid >> 6;
    const int m = lane & 15;
    const int q = lane >> 4;

    f32x4 acc[4][4] = {};
    const __bf16* __restrict__ wb = wbuf + WOFF;

    #pragma unroll
    for (int c = 0; c < K / 32; ++c) {
        bf16x8 a[4];
        #pragma unroll
        for (int mi = 0; mi < 4; ++mi)
            a[mi] = *reinterpret_cast<const bf16x8*>(
                        &ldsA[(mi * 16 + m) * LDA + c * 32 + q * 8]);
        #pragma unroll
        for (int ni = 0; ni < 4; ++ni) {
            int nt = wave * 4 + ni;
            bf16x8 b = *reinterpret_cast<const bf16x8*>(
                           wb + ((size_t)(c * 16 + nt) * 64 + lane) * 8);
            #pragma unroll
            for (int mi = 0; mi < 4; ++mi)
                acc[mi][ni] = __builtin_amdgcn_mfma_f32_16x16x32_bf16(
                                  a[mi], b, acc[mi][ni], 0, 0, 0);
        }
    }

    const f32x4 bias4 = *reinterpret_cast<const f32x4*>(&bias[lane * 4]);

    // Epilogue: transpose each 16-row subtile through LDS, store 1KB rows.
    #pragma unroll
    for (int mi = 0; mi < 4; ++mi) {
        __syncthreads();
        #pragma unroll
        for (int ni = 0; ni < 4; ++ni) {
            int col = (wave * 4 + ni) * 16 + m;
            #pragma unroll
            for (int r = 0; r < 4; ++r)
                ldsOut[(q * 4 + r) * 260 + col] = acc[mi][ni][r];  // C/D: row=(q*4+r), col=lane&15
        }
        __syncthreads();
        #pragma unroll
        for (int it = 0; it < 4; ++it) {
            int r = it * 4 + wave;
            int lrow = mi * 16 + r;
            if (lrow < mcount) {
                int g = lidx[lrow];
                f32x4 v = *reinterpret_cast<const f32x4*>(&ldsOut[r * 260 + lane * 4]);
                v += bias4;
                *reinterpret_cast<f32x4*>(&out[(size_t)g * 256 + lane * 4]) = v;
            }
        }
    }
}

// ---------------------------------------------------------------------------
extern "C" void kernel_launch(void* const* d_in, const int* in_sizes, int n_in,
                              void* d_out, int out_size, void* d_ws, size_t ws_size,
                              hipStream_t stream) {
    const float* feat  = (const float*)d_in[0];
    const int*   types = (const int*)d_in[1];
    const float* W0 = (const float*)d_in[2];
    const float* b0 = (const float*)d_in[3];
    const float* W1 = (const float*)d_in[4];
    const float* b1 = (const float*)d_in[5];
    const float* W2 = (const float*)d_in[6];
    const float* b2 = (const float*)d_in[7];
    const float* W3 = (const float*)d_in[8];
    const float* b3 = (const float*)d_in[9];
    float* out = (float*)d_out;
    const int n = in_sizes[0] / 128;   // 500000 vertices

    char* ws = (char*)d_ws;
    int* ws_i    = (int*)ws;
    int* counts  = ws_i;           // byte 0
    int* cursors = ws_i + 4;       // byte 16
    int* bases   = ws_i + 8;       // byte 32
    int* idx     = ws_i + 16;      // byte 64
    __bf16* wbuf = (__bf16*)(ws + WS_WBUF_BYTES);

    hipMemsetAsync(counts, 0, 48, stream);
    count_kernel<<<489, 256, 0, stream>>>(types, n, counts);
    bases_kernel<<<1, 64, 0, stream>>>(counts, bases, cursors);
    scatter_kernel<<<(n + 1023) / 1024, 256, 0, stream>>>(types, n, cursors, idx);
    wswz_kernel<<<320, 256, 0, stream>>>(W0, W1, W2, W3, wbuf);

    const int tiles = (n + 63) / 64;   // upper bound per type; blocks early-exit
    gemm_kernel<0,  64,     0><<<tiles, 256, 0, stream>>>(feat, ws_i, wbuf, b0, out);
    gemm_kernel<1, 128, 16384><<<tiles, 256, 0, stream>>>(feat, ws_i, wbuf, b1, out);
    gemm_kernel<2,  96, 49152><<<tiles, 256, 0, stream>>>(feat, ws_i, wbuf, b2, out);
    gemm_kernel<3,  32, 73728><<<tiles, 256, 0, stream>>>(feat, ws_i, wbuf, b3, out);
}